// Round 1
// baseline (277.281 us; speedup 1.0000x reference)
//
#include <hip/hip_runtime.h>

#define B_ 32
#define T_ 2048
#define D_ 512

// ---------------- K1: energy[b,t] = dot(key[b,t,:], q[b,:]) ----------------
// 8 rows per wave; q in registers (no LDS/barrier); 16 float4 loads in flight;
// multi-row butterfly reduce: 10 shuffles produce all 8 row sums on lanes 0..7.
__global__ __launch_bounds__(256) void energy_kernel(
    const float* __restrict__ q,
    const float* __restrict__ key,
    float* __restrict__ energy)
{
    const int b    = blockIdx.x >> 6;          // 64 blocks per batch
    const int blk  = blockIdx.x & 63;
    const int wave = threadIdx.x >> 6;
    const int lane = threadIdx.x & 63;
    const int t0   = blk * 32 + wave * 8;      // first of this wave's 8 rows

    const float4* q4 = (const float4*)q + b * 128;
    const float4 qv0 = q4[lane];               // hot in L1/L2 after first block
    const float4 qv1 = q4[64 + lane];

    const float4* k4 = (const float4*)key + (size_t)(b * T_ + t0) * 128;

    float a[8];
#pragma unroll
    for (int r = 0; r < 8; ++r) {
        const float4 k0 = k4[r * 128 + lane];
        const float4 k1 = k4[r * 128 + 64 + lane];
        a[r] = k0.x * qv0.x + k0.y * qv0.y + k0.z * qv0.z + k0.w * qv0.w
             + k1.x * qv1.x + k1.y * qv1.y + k1.z * qv1.z + k1.w * qv1.w;
    }

    // Fold 8 values: after 3 select-exchange steps, lane holds row (lane&7)'s
    // partial; 3 plain xor steps finish the 64-lane sum.
#pragma unroll
    for (int i = 0; i < 4; ++i) {
        const float send = (lane & 1) ? a[2 * i] : a[2 * i + 1];
        const float keep = (lane & 1) ? a[2 * i + 1] : a[2 * i];
        a[i] = keep + __shfl_xor(send, 1);
    }
#pragma unroll
    for (int i = 0; i < 2; ++i) {
        const float send = (lane & 2) ? a[2 * i] : a[2 * i + 1];
        const float keep = (lane & 2) ? a[2 * i + 1] : a[2 * i];
        a[i] = keep + __shfl_xor(send, 2);
    }
    {
        const float send = (lane & 4) ? a[0] : a[1];
        const float keep = (lane & 4) ? a[1] : a[0];
        a[0] = keep + __shfl_xor(send, 4);
    }
    a[0] += __shfl_xor(a[0], 8);
    a[0] += __shfl_xor(a[0], 16);
    a[0] += __shfl_xor(a[0], 32);

    if (lane < 8)
        energy[b * T_ + t0 + lane] = a[0];     // coalesced 32B per wave
}

// ---------------- K2: fused softmax + context partial ----------------
// One block per (b, chunk of 128 rows): recompute full-row max/sum from energy
// (8 KiB redundant read, cheap), write this chunk's attn slice, then
// partial[b,chunk,:] = sum_{t in chunk} attn[b,t] * value[b,t,:].
__global__ __launch_bounds__(512) void ctx_kernel(
    const float* __restrict__ energy,
    const float* __restrict__ value,
    float* __restrict__ attn,                  // [B, T] region of d_out
    float* __restrict__ partial)               // [B, 16, D]
{
    __shared__ float  red_m[8];
    __shared__ float  red_s[8];
    __shared__ float4 attn_s4[32];             // 128 attn weights
    __shared__ float4 red4[512];               // 4 groups x 128 float4

    const int b     = blockIdx.x >> 4;
    const int chunk = blockIdx.x & 15;
    const int t0    = chunk * 128;
    const int wave  = threadIdx.x >> 6;
    const int lane  = threadIdx.x & 63;

    // ---- full-row softmax stats (identical in every chunk-block of b) ----
    const float4* e4 = (const float4*)(energy + b * T_);
    const float4 ev  = e4[threadIdx.x];        // 512 threads cover all 2048
    float m = fmaxf(fmaxf(ev.x, ev.y), fmaxf(ev.z, ev.w));
#pragma unroll
    for (int off = 32; off >= 1; off >>= 1)
        m = fmaxf(m, __shfl_xor(m, off));
    if (lane == 0) red_m[wave] = m;
    __syncthreads();
    m = red_m[0];
#pragma unroll
    for (int w = 1; w < 8; ++w) m = fmaxf(m, red_m[w]);

    float s = expf(ev.x - m) + expf(ev.y - m) + expf(ev.z - m) + expf(ev.w - m);
#pragma unroll
    for (int off = 32; off >= 1; off >>= 1)
        s += __shfl_xor(s, off);
    if (lane == 0) red_s[wave] = s;
    __syncthreads();
    s = red_s[0] + red_s[1] + red_s[2] + red_s[3]
      + red_s[4] + red_s[5] + red_s[6] + red_s[7];
    const float inv = 1.f / s;

    // ---- attention weights for this chunk: write global + stage in LDS ----
    if (threadIdx.x < 32) {
        const float4 ec = e4[chunk * 32 + threadIdx.x];
        float4 p;
        p.x = expf(ec.x - m) * inv;
        p.y = expf(ec.y - m) * inv;
        p.z = expf(ec.z - m) * inv;
        p.w = expf(ec.w - m) * inv;
        ((float4*)(attn + b * T_ + t0))[threadIdx.x] = p;
        attn_s4[threadIdx.x] = p;
    }
    __syncthreads();

    // ---- context partial: 4 row-groups x 128 float4 d-slices ----
    const int tg = threadIdx.x >> 7;           // row group 0..3
    const int d4 = threadIdx.x & 127;          // float4 index in D
    const float* attn_s = (const float*)attn_s4;

    const float4* v4 = (const float4*)value + (size_t)(b * T_ + t0 + tg) * 128 + d4;
    float4 acc = {0.f, 0.f, 0.f, 0.f};
#pragma unroll 8
    for (int i = 0; i < 32; ++i) {             // t = t0 + 4*i + tg
        const float aw  = attn_s[4 * i + tg];  // wave-uniform broadcast
        const float4 vv = v4[i * 4 * (D_ / 4)];
        acc.x += aw * vv.x; acc.y += aw * vv.y;
        acc.z += aw * vv.z; acc.w += aw * vv.w;
    }

    red4[tg * 128 + d4] = acc;
    __syncthreads();
    if (threadIdx.x < 128) {
        float4 a0 = red4[threadIdx.x +   0];
        float4 a1 = red4[threadIdx.x + 128];
        float4 a2 = red4[threadIdx.x + 256];
        float4 a3 = red4[threadIdx.x + 384];
        float4 sv;
        sv.x = a0.x + a1.x + a2.x + a3.x;
        sv.y = a0.y + a1.y + a2.y + a3.y;
        sv.z = a0.z + a1.z + a2.z + a3.z;
        sv.w = a0.w + a1.w + a2.w + a3.w;
        ((float4*)partial)[(b * 16 + chunk) * 128 + threadIdx.x] = sv;
    }
}

// ---------------- K3: out[b,:] = sum over 16 chunk partials ----------------
__global__ __launch_bounds__(128) void reduce_kernel(
    const float* __restrict__ partial,
    float* __restrict__ out)
{
    const int b  = blockIdx.x;
    const int d4 = threadIdx.x;
    float4 s = {0.f, 0.f, 0.f, 0.f};
#pragma unroll
    for (int c = 0; c < 16; ++c) {
        float4 p = ((const float4*)partial)[(b * 16 + c) * 128 + d4];
        s.x += p.x; s.y += p.y; s.z += p.z; s.w += p.w;
    }
    ((float4*)out)[b * 128 + d4] = s;
}

extern "C" void kernel_launch(void* const* d_in, const int* in_sizes, int n_in,
                              void* d_out, int out_size, void* d_ws, size_t ws_size,
                              hipStream_t stream)
{
    const float* q     = (const float*)d_in[0];   // [B, D]
    const float* key   = (const float*)d_in[1];   // [B, T, D]
    const float* value = (const float*)d_in[2];   // [B, T, D]

    float* out  = (float*)d_out;                  // [B, D] first
    float* attn = out + B_ * D_;                  // [B, T] second

    float* energy  = (float*)d_ws;                // B*T floats    (256 KiB)
    float* partial = energy + B_ * T_;            // B*16*D floats (1 MiB)

    energy_kernel<<<B_ * 64, 256, 0, stream>>>(q, key, energy);
    ctx_kernel<<<B_ * 16, 512, 0, stream>>>(energy, value, attn, partial);
    reduce_kernel<<<B_, 128, 0, stream>>>(partial, out);
}